// Round 1
// baseline (1188.766 us; speedup 1.0000x reference)
//
#include <hip/hip_runtime.h>
#include <hip/hip_bf16.h>

#define HID 96
#define NGRAPHS 64

// ---------------------------------------------------------------- degree ----
__global__ void deg_kernel(const int* __restrict__ dst, float* __restrict__ deg,
                           int n_edges) {
    int e = blockIdx.x * blockDim.x + threadIdx.x;
    if (e < n_edges) atomicAdd(&deg[dst[e]], 1.0f);
}

__global__ void dinv_kernel(float* __restrict__ deg, int n) {
    int i = blockIdx.x * blockDim.x + threadIdx.x;
    if (i < n) deg[i] = 1.0f / sqrtf(deg[i] + 1.0f);
}

// ---------------------------------------------------------------- GEMM ------
// out[N,96] = X[N,96] @ W[96,96].  W staged in LDS; 4 rows per block.
__global__ __launch_bounds__(384) void gemm_xw(const float* __restrict__ X,
                                               const float* __restrict__ W,
                                               float* __restrict__ out, int N) {
    __shared__ float Wl[HID * HID];
    __shared__ float Xl[4 * HID];
    int t = threadIdx.y * HID + threadIdx.x;
    for (int i = t; i < HID * HID; i += 4 * HID) Wl[i] = W[i];
    int row = blockIdx.x * 4 + threadIdx.y;
    if (row < N) Xl[threadIdx.y * HID + threadIdx.x] = X[(size_t)row * HID + threadIdx.x];
    __syncthreads();
    if (row >= N) return;
    int c = threadIdx.x;
    float acc = 0.0f;
    const float* xr = &Xl[threadIdx.y * HID];
#pragma unroll
    for (int k = 0; k < HID; k++) acc += xr[k] * Wl[k * HID + c];
    out[(size_t)row * HID + c] = acc;
}

// ---------------------------------------------------------------- scatter ---
// One 32-lane group per edge; each lane handles 3 features (coalesced).
__global__ __launch_bounds__(256) void edge_scatter(
    const float* __restrict__ h, const int* __restrict__ src,
    const int* __restrict__ dst, const float* __restrict__ dinv,
    float* __restrict__ agg, int n_edges) {
    int t = blockIdx.x * blockDim.x + threadIdx.x;
    int e = t >> 5;
    int lane = t & 31;
    if (e >= n_edges) return;
    int s = src[e];
    int d = dst[e];
    float norm = dinv[s] * dinv[d];
    const float* hrow = h + (size_t)s * HID;
    float* orow = agg + (size_t)d * HID;
#pragma unroll
    for (int c = 0; c < 3; c++) {
        int f = lane + 32 * c;
        atomicAdd(&orow[f], hrow[f] * norm);
    }
}

// ------------------------------------------------- self-loop + bias + act ---
__global__ __launch_bounds__(384) void selfloop_bias_act(
    float* __restrict__ agg, const float* __restrict__ h,
    const float* __restrict__ dinv, const float* __restrict__ b, int N,
    int do_relu) {
    int n = blockIdx.x * 4 + threadIdx.y;
    if (n >= N) return;
    int f = threadIdx.x;
    float di = dinv[n];
    size_t idx = (size_t)n * HID + f;
    float v = agg[idx] + h[idx] * di * di + b[f];
    agg[idx] = do_relu ? fmaxf(v, 0.0f) : v;
}

// ---------------------------------------------------------------- pooling ---
// batch is sorted: run-length accumulate per 256-node chunk, flush via atomics.
__global__ __launch_bounds__(96) void pool_kernel(
    const float* __restrict__ h, const int* __restrict__ batch,
    float* __restrict__ sums, float* __restrict__ cnts, int N) {
    const int CH = 256;
    int n0 = blockIdx.x * CH;
    if (n0 >= N) return;
    int f = threadIdx.x;
    int nend = min(n0 + CH, N);
    int g_cur = batch[n0];
    float acc = 0.0f, cacc = 0.0f;
    for (int n = n0; n < nend; n++) {
        int g = batch[n];
        if (g != g_cur) {
            atomicAdd(&sums[g_cur * HID + f], acc);
            if (f == 0) atomicAdd(&cnts[g_cur], cacc);
            acc = 0.0f;
            cacc = 0.0f;
            g_cur = g;
        }
        acc += h[(size_t)n * HID + f];
        cacc += 1.0f;
    }
    atomicAdd(&sums[g_cur * HID + f], acc);
    if (f == 0) atomicAdd(&cnts[g_cur], cacc);
}

// ---------------------------------------------------------------- head ------
__global__ __launch_bounds__(640) void final_kernel(
    const float* __restrict__ sums, const float* __restrict__ cnts,
    const float* __restrict__ Wlin, const float* __restrict__ blin,
    float* __restrict__ out) {
    int t = threadIdx.x;
    if (t >= NGRAPHS * 10) return;
    int g = t / 10;
    int c = t % 10;
    float denom = fmaxf(cnts[g], 1.0f);
    float acc = blin[c];
#pragma unroll
    for (int f = 0; f < HID; f++)
        acc += (sums[g * HID + f] / denom) * Wlin[f * 10 + c];
    out[t] = acc;
}

// ---------------------------------------------------------------- launch ----
extern "C" void kernel_launch(void* const* d_in, const int* in_sizes, int n_in,
                              void* d_out, int out_size, void* d_ws,
                              size_t ws_size, hipStream_t stream) {
    const float* x = (const float*)d_in[0];
    const int* edge = (const int*)d_in[1];
    const int* batch = (const int*)d_in[2];
    const float* W[3] = {(const float*)d_in[3], (const float*)d_in[5],
                         (const float*)d_in[7]};
    const float* B[3] = {(const float*)d_in[4], (const float*)d_in[6],
                         (const float*)d_in[8]};
    const float* Wlin = (const float*)d_in[9];
    const float* blin = (const float*)d_in[10];
    float* out = (float*)d_out;

    int N = in_sizes[0] / HID;        // 50000
    int E = in_sizes[1] / 2;          // 800000
    const int* src = edge;
    const int* dst = edge + E;

    // workspace layout (floats)
    float* ws = (float*)d_ws;
    size_t off = 0;
    float* deg = ws + off;  off += ((size_t)N + 255) & ~255ull;       // dinv after kernel 2
    float* bufh = ws + off; off += (size_t)N * HID;
    float* bufa = ws + off; off += (size_t)N * HID;
    float* psum = ws + off; off += NGRAPHS * HID;
    float* pcnt = ws + off; off += NGRAPHS;

    // degree -> dinv
    hipMemsetAsync(deg, 0, (size_t)N * sizeof(float), stream);
    deg_kernel<<<(E + 255) / 256, 256, 0, stream>>>(dst, deg, E);
    dinv_kernel<<<(N + 255) / 256, 256, 0, stream>>>(deg, N);

    dim3 gemm_blk(HID, 4);
    dim3 ew_blk(HID, 4);
    int gemm_grid = (N + 3) / 4;
    int scat_grid = ((size_t)E * 32 + 255) / 256;

    const float* layer_in = x;
    for (int l = 0; l < 3; l++) {
        gemm_xw<<<gemm_grid, gemm_blk, 0, stream>>>(layer_in, W[l], bufh, N);
        hipMemsetAsync(bufa, 0, (size_t)N * HID * sizeof(float), stream);
        edge_scatter<<<scat_grid, 256, 0, stream>>>(bufh, src, dst, deg, bufa, E);
        selfloop_bias_act<<<gemm_grid, ew_blk, 0, stream>>>(bufa, bufh, deg,
                                                            B[l], N, l < 2);
        layer_in = bufa;
    }

    // pooling
    hipMemsetAsync(psum, 0, (NGRAPHS * HID + NGRAPHS) * sizeof(float), stream);
    pool_kernel<<<(N + 255) / 256, 96, 0, stream>>>(bufa, batch, psum, pcnt, N);
    final_kernel<<<1, 640, 0, stream>>>(psum, pcnt, Wlin, blin, out);
}

// Round 2
// 926.358 us; speedup vs baseline: 1.2833x; 1.2833x over previous
//
#include <hip/hip_runtime.h>
#include <hip/hip_bf16.h>

#define HID 96
#define NGRAPHS 64

// ---------------------------------------------------------------- degree ----
__global__ void deg_kernel(const int* __restrict__ dst, int* __restrict__ deg,
                           int n_edges) {
    int e = blockIdx.x * blockDim.x + threadIdx.x;
    if (e < n_edges) atomicAdd(&deg[dst[e]], 1);
}

__global__ void dinv_kernel(const int* __restrict__ deg, float* __restrict__ dinv,
                            int n) {
    int i = blockIdx.x * blockDim.x + threadIdx.x;
    if (i < n) dinv[i] = rsqrtf((float)deg[i] + 1.0f);
}

// ------------------------------------------------------------------ scan ----
// Exclusive prefix sum of deg[N] -> rowptr[N+1]. Single block, 1024 threads.
__global__ __launch_bounds__(1024) void scan_kernel(const int* __restrict__ deg,
                                                    int* __restrict__ rowptr,
                                                    int N, int E) {
    __shared__ int sums[1024];
    int t = threadIdx.x;
    int per = (N + 1023) / 1024;
    int lo = t * per;
    int hi = min(lo + per, N);
    int local = 0;
    for (int i = lo; i < hi; i++) local += deg[i];
    sums[t] = local;
    __syncthreads();
    // Hillis-Steele inclusive scan
    for (int off = 1; off < 1024; off <<= 1) {
        int v = (t >= off) ? sums[t - off] : 0;
        __syncthreads();
        sums[t] += v;
        __syncthreads();
    }
    int running = sums[t] - local;  // exclusive offset for this chunk
    for (int i = lo; i < hi; i++) {
        rowptr[i] = running;
        running += deg[i];
    }
    if (t == 0) rowptr[N] = E;
}

// ------------------------------------------------------------------ fill ----
__global__ void csr_fill(const int* __restrict__ src, const int* __restrict__ dst,
                         const int* __restrict__ rowptr, int* __restrict__ cursor,
                         int* __restrict__ csr_src, int n_edges) {
    int e = blockIdx.x * blockDim.x + threadIdx.x;
    if (e >= n_edges) return;
    int d = dst[e];
    int pos = atomicAdd(&cursor[d], 1);
    csr_src[rowptr[d] + pos] = src[e];
}

// ---------------------------------------------------------------- GEMM ------
// out[N,96] = X[N,96] @ W[96,96].  W staged in LDS; 4 rows per block.
__global__ __launch_bounds__(384) void gemm_xw(const float* __restrict__ X,
                                               const float* __restrict__ W,
                                               float* __restrict__ out, int N) {
    __shared__ float Wl[HID * HID];
    __shared__ float Xl[4 * HID];
    int t = threadIdx.y * HID + threadIdx.x;
    for (int i = t; i < HID * HID; i += 4 * HID) Wl[i] = W[i];
    int row = blockIdx.x * 4 + threadIdx.y;
    if (row < N) Xl[threadIdx.y * HID + threadIdx.x] = X[(size_t)row * HID + threadIdx.x];
    __syncthreads();
    if (row >= N) return;
    int c = threadIdx.x;
    float acc = 0.0f;
    const float* xr = &Xl[threadIdx.y * HID];
#pragma unroll
    for (int k = 0; k < HID; k++) acc += xr[k] * Wl[k * HID + c];
    out[(size_t)row * HID + c] = acc;
}

// ---------------------------------------------------------------- gather ----
// One 96-thread group per node: out[n][f] = sum_{e in CSR[n]} h[src][f]*dinv[src]*dinv[n]
//                                           + h[n][f]*dinv[n]^2 + b[f]  (+relu)
__global__ __launch_bounds__(384) void gcn_gather(
    const float* __restrict__ h, const int* __restrict__ rowptr,
    const int* __restrict__ csr_src, const float* __restrict__ dinv,
    const float* __restrict__ b, float* __restrict__ out, int N, int do_relu) {
    int n = blockIdx.x * 4 + threadIdx.y;
    if (n >= N) return;
    int f = threadIdx.x;
    int start = rowptr[n];
    int end = rowptr[n + 1];
    float di = dinv[n];
    float acc = h[(size_t)n * HID + f] * di * di;  // self-loop
    for (int i = start; i < end; i++) {
        int s = csr_src[i];
        acc += h[(size_t)s * HID + f] * (dinv[s] * di);
    }
    float v = acc + b[f];
    out[(size_t)n * HID + f] = do_relu ? fmaxf(v, 0.0f) : v;
}

// ---------------------------------------------------------------- pooling ---
__global__ __launch_bounds__(96) void pool_kernel(
    const float* __restrict__ h, const int* __restrict__ batch,
    float* __restrict__ sums, float* __restrict__ cnts, int N) {
    const int CH = 256;
    int n0 = blockIdx.x * CH;
    if (n0 >= N) return;
    int f = threadIdx.x;
    int nend = min(n0 + CH, N);
    int g_cur = batch[n0];
    float acc = 0.0f, cacc = 0.0f;
    for (int n = n0; n < nend; n++) {
        int g = batch[n];
        if (g != g_cur) {
            atomicAdd(&sums[g_cur * HID + f], acc);
            if (f == 0) atomicAdd(&cnts[g_cur], cacc);
            acc = 0.0f;
            cacc = 0.0f;
            g_cur = g;
        }
        acc += h[(size_t)n * HID + f];
        cacc += 1.0f;
    }
    atomicAdd(&sums[g_cur * HID + f], acc);
    if (f == 0) atomicAdd(&cnts[g_cur], cacc);
}

// ---------------------------------------------------------------- head ------
__global__ __launch_bounds__(640) void final_kernel(
    const float* __restrict__ sums, const float* __restrict__ cnts,
    const float* __restrict__ Wlin, const float* __restrict__ blin,
    float* __restrict__ out) {
    int t = threadIdx.x;
    if (t >= NGRAPHS * 10) return;
    int g = t / 10;
    int c = t % 10;
    float denom = fmaxf(cnts[g], 1.0f);
    float acc = blin[c];
#pragma unroll
    for (int f = 0; f < HID; f++)
        acc += (sums[g * HID + f] / denom) * Wlin[f * 10 + c];
    out[t] = acc;
}

// ---------------------------------------------------------------- launch ----
extern "C" void kernel_launch(void* const* d_in, const int* in_sizes, int n_in,
                              void* d_out, int out_size, void* d_ws,
                              size_t ws_size, hipStream_t stream) {
    const float* x = (const float*)d_in[0];
    const int* edge = (const int*)d_in[1];
    const int* batch = (const int*)d_in[2];
    const float* W[3] = {(const float*)d_in[3], (const float*)d_in[5],
                         (const float*)d_in[7]};
    const float* B[3] = {(const float*)d_in[4], (const float*)d_in[6],
                         (const float*)d_in[8]};
    const float* Wlin = (const float*)d_in[9];
    const float* blin = (const float*)d_in[10];
    float* out = (float*)d_out;

    int N = in_sizes[0] / HID;  // 50000
    int E = in_sizes[1] / 2;    // 800000
    const int* src = edge;
    const int* dst = edge + E;

    // workspace layout (4-byte units)
    char* ws = (char*)d_ws;
    size_t off = 0;
    int* deg = (int*)(ws + off);        off += (size_t)N * 4;
    float* dinv = (float*)(ws + off);   off += (size_t)N * 4;
    int* rowptr = (int*)(ws + off);     off += ((size_t)N + 1) * 4;
    int* cursor = (int*)(ws + off);     off += (size_t)N * 4;
    int* csr_src = (int*)(ws + off);    off += (size_t)E * 4;
    float* bufh = (float*)(ws + off);   off += (size_t)N * HID * 4;
    float* bufa = (float*)(ws + off);   off += (size_t)N * HID * 4;
    float* psum = (float*)(ws + off);   off += NGRAPHS * HID * 4;
    float* pcnt = (float*)(ws + off);   off += NGRAPHS * 4;

    // --- CSR build (once, reused by all 3 layers) ---
    hipMemsetAsync(deg, 0, (size_t)N * 2 * 4 + 4, stream);  // deg + dinv area (dinv overwritten anyway)
    hipMemsetAsync(cursor, 0, (size_t)N * 4, stream);
    deg_kernel<<<(E + 255) / 256, 256, 0, stream>>>(dst, deg, E);
    dinv_kernel<<<(N + 255) / 256, 256, 0, stream>>>(deg, dinv, N);
    scan_kernel<<<1, 1024, 0, stream>>>(deg, rowptr, N, E);
    csr_fill<<<(E + 255) / 256, 256, 0, stream>>>(src, dst, rowptr, cursor,
                                                  csr_src, E);

    dim3 blk96x4(HID, 4);
    int grid_n4 = (N + 3) / 4;

    const float* layer_in = x;
    for (int l = 0; l < 3; l++) {
        gemm_xw<<<grid_n4, blk96x4, 0, stream>>>(layer_in, W[l], bufh, N);
        gcn_gather<<<grid_n4, blk96x4, 0, stream>>>(bufh, rowptr, csr_src, dinv,
                                                    B[l], bufa, N, l < 2);
        layer_in = bufa;
    }

    // pooling
    hipMemsetAsync(psum, 0, (NGRAPHS * HID + NGRAPHS) * sizeof(float), stream);
    pool_kernel<<<(N + 255) / 256, 96, 0, stream>>>(bufa, batch, psum, pcnt, N);
    final_kernel<<<1, 640, 0, stream>>>(psum, pcnt, Wlin, blin, out);
}

// Round 3
// 488.551 us; speedup vs baseline: 2.4333x; 1.8961x over previous
//
#include <hip/hip_runtime.h>
#include <hip/hip_bf16.h>

#define HID 96
#define NGRAPHS 64

typedef __attribute__((ext_vector_type(8))) short short8;
typedef __attribute__((ext_vector_type(4))) float floatx4;

__device__ __forceinline__ float bf16_to_f32(unsigned short u) {
    unsigned int v = ((unsigned int)u) << 16;
    return __builtin_bit_cast(float, v);
}
__device__ __forceinline__ unsigned short f32_to_bf16(float f) {
    unsigned int u = __builtin_bit_cast(unsigned int, f);
    u += 0x7fff + ((u >> 16) & 1);  // RNE
    return (unsigned short)(u >> 16);
}

// ---------------------------------------------------------------- degree ----
__global__ void deg_kernel(const int* __restrict__ dst, int* __restrict__ deg,
                           int n_edges) {
    int e = blockIdx.x * blockDim.x + threadIdx.x;
    if (e < n_edges) atomicAdd(&deg[dst[e]], 1);
}

__global__ void dinv_kernel(const int* __restrict__ deg, float* __restrict__ dinv,
                            int n) {
    int i = blockIdx.x * blockDim.x + threadIdx.x;
    if (i < n) dinv[i] = rsqrtf((float)deg[i] + 1.0f);
}

// ------------------------------------------------------------------ scan ----
__global__ __launch_bounds__(1024) void scan_kernel(const int* __restrict__ deg,
                                                    int* __restrict__ rowptr,
                                                    int N, int E) {
    __shared__ int sums[1024];
    int t = threadIdx.x;
    int per = (N + 1023) / 1024;
    int lo = t * per;
    int hi = min(lo + per, N);
    int local = 0;
    for (int i = lo; i < hi; i++) local += deg[i];
    sums[t] = local;
    __syncthreads();
    for (int off = 1; off < 1024; off <<= 1) {
        int v = (t >= off) ? sums[t - off] : 0;
        __syncthreads();
        sums[t] += v;
        __syncthreads();
    }
    int running = sums[t] - local;
    for (int i = lo; i < hi; i++) {
        rowptr[i] = running;
        running += deg[i];
    }
    if (t == 0) rowptr[N] = E;
}

// ------------------------------------------------------------------ fill ----
__global__ void csr_fill(const int* __restrict__ src, const int* __restrict__ dst,
                         const int* __restrict__ rowptr, int* __restrict__ cursor,
                         int* __restrict__ csr_src, int n_edges) {
    int e = blockIdx.x * blockDim.x + threadIdx.x;
    if (e >= n_edges) return;
    int d = dst[e];
    int pos = atomicAdd(&cursor[d], 1);
    csr_src[rowptr[d] + pos] = src[e];
}

// --------------------------------------------------------------- convert ----
__global__ void cvt_f32_bf16(const float* __restrict__ in,
                             unsigned short* __restrict__ out, int n) {
    int i = blockIdx.x * blockDim.x + threadIdx.x;
    if (i < n) out[i] = f32_to_bf16(in[i]);
}

// W[96][96] f32 -> bf16 in MFMA B-fragment order.
// frag f = nt*3 + kki (nt = n/16, kki = k/32); within frag: lane = (n&15)|(quad<<4),
// quad = (k>>3)&3, j = k&7. Element stored at (f*64 + lane)*8 + j.
__global__ void swizzle_W(const float* __restrict__ W0, const float* __restrict__ W1,
                          const float* __restrict__ W2, unsigned short* __restrict__ Wz) {
    const float* W = (blockIdx.x == 0) ? W0 : (blockIdx.x == 1) ? W1 : W2;
    unsigned short* dst = Wz + blockIdx.x * HID * HID;
    for (int e = threadIdx.x; e < HID * HID; e += blockDim.x) {
        int k = e / HID, n = e % HID;
        int nt = n >> 4, kki = k >> 5, quad = (k >> 3) & 3, j = k & 7;
        int lane = (n & 15) | (quad << 4);
        dst[(((nt * 3 + kki) * 64 + lane) << 3) | j] = f32_to_bf16(W[e]);
    }
}

// ------------------------------------------------------------- MFMA GEMM ----
// Out[N,96](bf16) = A[N,96](bf16) @ W(bf16, swizzled). 4 waves/block, each wave
// computes 16 rows x 96 cols per grid-stride step. B-frags held in VGPRs.
__global__ __launch_bounds__(256) void gemm_mfma(
    const unsigned short* __restrict__ A, const unsigned short* __restrict__ Wz,
    unsigned short* __restrict__ Out, int Mtiles) {
    int wave = threadIdx.x >> 6;
    int lane = threadIdx.x & 63;
    int quad = lane >> 4;
    int mrow = lane & 15;

    short8 bfrag[18];
    const short8* Wz8 = (const short8*)Wz;
#pragma unroll
    for (int f = 0; f < 18; f++) bfrag[f] = Wz8[f * 64 + lane];

    for (int tt = blockIdx.x * 4 + wave; tt < Mtiles; tt += gridDim.x * 4) {
        int m0 = tt * 16;
        const unsigned short* arow = A + (size_t)(m0 + mrow) * HID + quad * 8;
        short8 a0 = *(const short8*)(arow);
        short8 a1 = *(const short8*)(arow + 32);
        short8 a2 = *(const short8*)(arow + 64);
        floatx4 acc[6];
#pragma unroll
        for (int nt = 0; nt < 6; nt++) {
            floatx4 c = {0.0f, 0.0f, 0.0f, 0.0f};
            c = __builtin_amdgcn_mfma_f32_16x16x32_bf16(a0, bfrag[nt * 3 + 0], c, 0, 0, 0);
            c = __builtin_amdgcn_mfma_f32_16x16x32_bf16(a1, bfrag[nt * 3 + 1], c, 0, 0, 0);
            c = __builtin_amdgcn_mfma_f32_16x16x32_bf16(a2, bfrag[nt * 3 + 2], c, 0, 0, 0);
            acc[nt] = c;
        }
        unsigned short* orow = Out + (size_t)m0 * HID;
#pragma unroll
        for (int nt = 0; nt < 6; nt++)
#pragma unroll
            for (int r = 0; r < 4; r++) {
                int row = quad * 4 + r;  // C/D: col=lane&15, row=quad*4+reg
                orow[(size_t)row * HID + nt * 16 + mrow] = f32_to_bf16(acc[nt][r]);
            }
    }
}

// ---------------------------------------------------------------- gather ----
// One wave per node; lanes 0..47 each own 2 features (ushort2 = 4B loads).
__global__ __launch_bounds__(256) void gcn_gather_bf16(
    const unsigned short* __restrict__ h, const int* __restrict__ rowptr,
    const int* __restrict__ csr_src, const float* __restrict__ dinv,
    const float* __restrict__ b, unsigned short* __restrict__ out, int N,
    int do_relu) {
    int wv = threadIdx.x >> 6;
    int lane = threadIdx.x & 63;
    int n = blockIdx.x * 4 + wv;
    if (n >= N) return;
    int fi = (lane < 48) ? lane * 2 : 0;  // clamp idle lanes to f0 (no OOB)
    int start = rowptr[n];
    int end = rowptr[n + 1];
    float di = dinv[n];

    // self-loop
    ushort2 hv = *(const ushort2*)(h + (size_t)n * HID + fi);
    float w = di * di;
    float acc0 = w * bf16_to_f32(hv.x);
    float acc1 = w * bf16_to_f32(hv.y);

#pragma unroll 4
    for (int i = start; i < end; i++) {
        int s = csr_src[i];
        float ws_ = dinv[s] * di;
        ushort2 v = *(const ushort2*)(h + (size_t)s * HID + fi);
        acc0 += ws_ * bf16_to_f32(v.x);
        acc1 += ws_ * bf16_to_f32(v.y);
    }
    acc0 += b[fi];
    acc1 += b[fi + 1];
    if (do_relu) {
        acc0 = fmaxf(acc0, 0.0f);
        acc1 = fmaxf(acc1, 0.0f);
    }
    if (lane < 48) {
        ushort2 o;
        o.x = f32_to_bf16(acc0);
        o.y = f32_to_bf16(acc1);
        *(ushort2*)(out + (size_t)n * HID + fi) = o;
    }
}

// ---------------------------------------------------------------- pooling ---
__global__ __launch_bounds__(96) void pool_kernel(
    const unsigned short* __restrict__ h, const int* __restrict__ batch,
    float* __restrict__ sums, float* __restrict__ cnts, int N) {
    const int CH = 256;
    int n0 = blockIdx.x * CH;
    if (n0 >= N) return;
    int f = threadIdx.x;
    int nend = min(n0 + CH, N);
    int g_cur = batch[n0];
    float acc = 0.0f, cacc = 0.0f;
    for (int n = n0; n < nend; n++) {
        int g = batch[n];
        if (g != g_cur) {
            atomicAdd(&sums[g_cur * HID + f], acc);
            if (f == 0) atomicAdd(&cnts[g_cur], cacc);
            acc = 0.0f;
            cacc = 0.0f;
            g_cur = g;
        }
        acc += bf16_to_f32(h[(size_t)n * HID + f]);
        cacc += 1.0f;
    }
    atomicAdd(&sums[g_cur * HID + f], acc);
    if (f == 0) atomicAdd(&cnts[g_cur], cacc);
}

// ---------------------------------------------------------------- head ------
__global__ __launch_bounds__(640) void final_kernel(
    const float* __restrict__ sums, const float* __restrict__ cnts,
    const float* __restrict__ Wlin, const float* __restrict__ blin,
    float* __restrict__ out) {
    int t = threadIdx.x;
    if (t >= NGRAPHS * 10) return;
    int g = t / 10;
    int c = t % 10;
    float denom = fmaxf(cnts[g], 1.0f);
    float acc = blin[c];
#pragma unroll
    for (int f = 0; f < HID; f++)
        acc += (sums[g * HID + f] / denom) * Wlin[f * 10 + c];
    out[t] = acc;
}

// ---------------------------------------------------------------- launch ----
extern "C" void kernel_launch(void* const* d_in, const int* in_sizes, int n_in,
                              void* d_out, int out_size, void* d_ws,
                              size_t ws_size, hipStream_t stream) {
    const float* x = (const float*)d_in[0];
    const int* edge = (const int*)d_in[1];
    const int* batch = (const int*)d_in[2];
    const float* W[3] = {(const float*)d_in[3], (const float*)d_in[5],
                         (const float*)d_in[7]};
    const float* B[3] = {(const float*)d_in[4], (const float*)d_in[6],
                         (const float*)d_in[8]};
    const float* Wlin = (const float*)d_in[9];
    const float* blin = (const float*)d_in[10];
    float* out = (float*)d_out;

    int N = in_sizes[0] / HID;  // 50000
    int E = in_sizes[1] / 2;    // 800000
    const int* src = edge;
    const int* dst = edge + E;

    // workspace layout (256B-aligned chunks)
    char* ws = (char*)d_ws;
    size_t off = 0;
    auto alloc = [&](size_t bytes) {
        void* p = ws + off;
        off += (bytes + 255) & ~(size_t)255;
        return p;
    };
    int* deg = (int*)alloc((size_t)N * 4);
    float* dinv = (float*)alloc((size_t)N * 4);
    int* rowptr = (int*)alloc(((size_t)N + 1) * 4);
    int* cursor = (int*)alloc((size_t)N * 4);
    int* csr_src = (int*)alloc((size_t)E * 4);
    unsigned short* Wz = (unsigned short*)alloc(3 * HID * HID * 2);
    unsigned short* bufx = (unsigned short*)alloc((size_t)N * HID * 2);
    unsigned short* bufh = (unsigned short*)alloc((size_t)N * HID * 2);
    unsigned short* bufa = (unsigned short*)alloc((size_t)N * HID * 2);
    float* psum = (float*)alloc(NGRAPHS * HID * 4);
    float* pcnt = (float*)alloc(NGRAPHS * 4);

    // --- CSR build + weight prep ---
    hipMemsetAsync(deg, 0, (size_t)N * 4, stream);
    hipMemsetAsync(cursor, 0, (size_t)N * 4, stream);
    deg_kernel<<<(E + 255) / 256, 256, 0, stream>>>(dst, deg, E);
    dinv_kernel<<<(N + 255) / 256, 256, 0, stream>>>(deg, dinv, N);
    scan_kernel<<<1, 1024, 0, stream>>>(deg, rowptr, N, E);
    csr_fill<<<(E + 255) / 256, 256, 0, stream>>>(src, dst, rowptr, cursor,
                                                  csr_src, E);
    swizzle_W<<<3, 256, 0, stream>>>(W[0], W[1], W[2], Wz);
    cvt_f32_bf16<<<((size_t)N * HID + 255) / 256, 256, 0, stream>>>(x, bufx,
                                                                    N * HID);

    int Mtiles = (N + 15) / 16;  // 3125
    int gather_grid = (N + 3) / 4;

    unsigned short* act_in = bufx;
    unsigned short* act_out = bufa;
    for (int l = 0; l < 3; l++) {
        gemm_mfma<<<320, 256, 0, stream>>>(act_in, Wz + l * HID * HID, bufh,
                                           Mtiles);
        gcn_gather_bf16<<<gather_grid, 256, 0, stream>>>(
            bufh, rowptr, csr_src, dinv, B[l], act_out, N, l < 2);
        // ping-pong: layer consumed act_in; reuse it as next output
        unsigned short* t = act_in;
        act_in = act_out;
        act_out = t;
    }
    // after 3 layers act_in holds the final activations
    hipMemsetAsync(psum, 0, (NGRAPHS * HID + NGRAPHS) * sizeof(float), stream);
    pool_kernel<<<(N + 255) / 256, 96, 0, stream>>>(act_in, batch, psum, pcnt, N);
    final_kernel<<<1, 640, 0, stream>>>(psum, pcnt, Wlin, blin, out);
}

// Round 4
// 368.049 us; speedup vs baseline: 3.2299x; 1.3274x over previous
//
#include <hip/hip_runtime.h>
#include <hip/hip_bf16.h>

#define HID 96
#define NGRAPHS 64

typedef __attribute__((ext_vector_type(8))) short short8;
typedef __attribute__((ext_vector_type(4))) float floatx4;

__device__ __forceinline__ float bf16_to_f32(unsigned short u) {
    unsigned int v = ((unsigned int)u) << 16;
    return __builtin_bit_cast(float, v);
}
__device__ __forceinline__ unsigned short f32_to_bf16(float f) {
    unsigned int u = __builtin_bit_cast(unsigned int, f);
    u += 0x7fff + ((u >> 16) & 1);  // RNE
    return (unsigned short)(u >> 16);
}

// ---------------------------------------------------------------- degree ----
__global__ void deg_kernel(const int* __restrict__ dst, int* __restrict__ deg,
                           int n_edges) {
    int e = blockIdx.x * blockDim.x + threadIdx.x;
    if (e < n_edges) atomicAdd(&deg[dst[e]], 1);
}

__global__ void dinv_kernel(const int* __restrict__ deg, float* __restrict__ dinv,
                            int n) {
    int i = blockIdx.x * blockDim.x + threadIdx.x;
    if (i < n) dinv[i] = rsqrtf((float)deg[i] + 1.0f);
}

// ---------------------------------------------------- 3-phase prefix scan ---
// A: per-256-block sums. B: 1-block scan of block sums. C: local scan+offset.
__global__ __launch_bounds__(256) void scan_phaseA(const int* __restrict__ deg,
                                                   int* __restrict__ blocksum,
                                                   int N) {
    int i = blockIdx.x * 256 + threadIdx.x;
    int v = (i < N) ? deg[i] : 0;
#pragma unroll
    for (int off = 32; off > 0; off >>= 1) v += __shfl_down(v, off, 64);
    __shared__ int s[4];
    if ((threadIdx.x & 63) == 0) s[threadIdx.x >> 6] = v;
    __syncthreads();
    if (threadIdx.x == 0) blocksum[blockIdx.x] = s[0] + s[1] + s[2] + s[3];
}

__global__ __launch_bounds__(256) void scan_phaseB(int* __restrict__ blocksum,
                                                   int* __restrict__ blockoff,
                                                   int nblocks, int* __restrict__ rowptr,
                                                   int N, int E) {
    __shared__ int s[256];
    int t = threadIdx.x;
    int own = (t < nblocks) ? blocksum[t] : 0;
    s[t] = own;
    __syncthreads();
#pragma unroll
    for (int off = 1; off < 256; off <<= 1) {
        int v = (t >= off) ? s[t - off] : 0;
        __syncthreads();
        s[t] += v;
        __syncthreads();
    }
    if (t < nblocks) blockoff[t] = s[t] - own;  // exclusive
    if (t == 0) rowptr[N] = E;
}

__global__ __launch_bounds__(256) void scan_phaseC(const int* __restrict__ deg,
                                                   const int* __restrict__ blockoff,
                                                   int* __restrict__ rowptr, int N) {
    __shared__ int s[256];
    int t = threadIdx.x;
    int i = blockIdx.x * 256 + t;
    int own = (i < N) ? deg[i] : 0;
    s[t] = own;
    __syncthreads();
#pragma unroll
    for (int off = 1; off < 256; off <<= 1) {
        int v = (t >= off) ? s[t - off] : 0;
        __syncthreads();
        s[t] += v;
        __syncthreads();
    }
    if (i < N) rowptr[i] = blockoff[blockIdx.x] + s[t] - own;
}

// ------------------------------------------------------------------ fill ----
__global__ void csr_fill(const int* __restrict__ src, const int* __restrict__ dst,
                         const int* __restrict__ rowptr, int* __restrict__ cursor,
                         int* __restrict__ csr_src, int n_edges) {
    int e = blockIdx.x * blockDim.x + threadIdx.x;
    if (e >= n_edges) return;
    int d = dst[e];
    int pos = atomicAdd(&cursor[d], 1);
    csr_src[rowptr[d] + pos] = src[e];
}

// --------------------------------------------------------------- convert ----
__global__ void cvt_f32_bf16(const float* __restrict__ in,
                             unsigned short* __restrict__ out, int n) {
    int i = blockIdx.x * blockDim.x + threadIdx.x;
    if (i < n) out[i] = f32_to_bf16(in[i]);
}

// W[96][96] f32 -> bf16 in MFMA B-fragment order.
__global__ void swizzle_W(const float* __restrict__ W0, const float* __restrict__ W1,
                          const float* __restrict__ W2, unsigned short* __restrict__ Wz) {
    const float* W = (blockIdx.x == 0) ? W0 : (blockIdx.x == 1) ? W1 : W2;
    unsigned short* dst = Wz + blockIdx.x * HID * HID;
    for (int e = threadIdx.x; e < HID * HID; e += blockDim.x) {
        int k = e / HID, n = e % HID;
        int nt = n >> 4, kki = k >> 5, quad = (k >> 3) & 3, j = k & 7;
        int lane = (n & 15) | (quad << 4);
        dst[(((nt * 3 + kki) * 64 + lane) << 3) | j] = f32_to_bf16(W[e]);
    }
}

// ------------------------------------------------------------- MFMA GEMM ----
__global__ __launch_bounds__(256) void gemm_mfma(
    const unsigned short* __restrict__ A, const unsigned short* __restrict__ Wz,
    unsigned short* __restrict__ Out, int Mtiles) {
    int wave = threadIdx.x >> 6;
    int lane = threadIdx.x & 63;
    int quad = lane >> 4;
    int mrow = lane & 15;

    short8 bfrag[18];
    const short8* Wz8 = (const short8*)Wz;
#pragma unroll
    for (int f = 0; f < 18; f++) bfrag[f] = Wz8[f * 64 + lane];

    for (int tt = blockIdx.x * 4 + wave; tt < Mtiles; tt += gridDim.x * 4) {
        int m0 = tt * 16;
        const unsigned short* arow = A + (size_t)(m0 + mrow) * HID + quad * 8;
        short8 a0 = *(const short8*)(arow);
        short8 a1 = *(const short8*)(arow + 32);
        short8 a2 = *(const short8*)(arow + 64);
        floatx4 acc[6];
#pragma unroll
        for (int nt = 0; nt < 6; nt++) {
            floatx4 c = {0.0f, 0.0f, 0.0f, 0.0f};
            c = __builtin_amdgcn_mfma_f32_16x16x32_bf16(a0, bfrag[nt * 3 + 0], c, 0, 0, 0);
            c = __builtin_amdgcn_mfma_f32_16x16x32_bf16(a1, bfrag[nt * 3 + 1], c, 0, 0, 0);
            c = __builtin_amdgcn_mfma_f32_16x16x32_bf16(a2, bfrag[nt * 3 + 2], c, 0, 0, 0);
            acc[nt] = c;
        }
        unsigned short* orow = Out + (size_t)m0 * HID;
#pragma unroll
        for (int nt = 0; nt < 6; nt++)
#pragma unroll
            for (int r = 0; r < 4; r++) {
                int row = quad * 4 + r;  // C/D: col=lane&15, row=quad*4+reg
                orow[(size_t)row * HID + nt * 16 + mrow] = f32_to_bf16(acc[nt][r]);
            }
    }
}

// ---------------------------------------------------------------- gather ----
__global__ __launch_bounds__(256) void gcn_gather_bf16(
    const unsigned short* __restrict__ h, const int* __restrict__ rowptr,
    const int* __restrict__ csr_src, const float* __restrict__ dinv,
    const float* __restrict__ b, unsigned short* __restrict__ out, int N,
    int do_relu) {
    int wv = threadIdx.x >> 6;
    int lane = threadIdx.x & 63;
    int n = blockIdx.x * 4 + wv;
    if (n >= N) return;
    int fi = (lane < 48) ? lane * 2 : 0;  // clamp idle lanes (no OOB)
    int start = rowptr[n];
    int end = rowptr[n + 1];
    float di = dinv[n];

    ushort2 hv = *(const ushort2*)(h + (size_t)n * HID + fi);
    float w = di * di;
    float acc0 = w * bf16_to_f32(hv.x);
    float acc1 = w * bf16_to_f32(hv.y);

#pragma unroll 4
    for (int i = start; i < end; i++) {
        int s = csr_src[i];
        float ws_ = dinv[s] * di;
        ushort2 v = *(const ushort2*)(h + (size_t)s * HID + fi);
        acc0 += ws_ * bf16_to_f32(v.x);
        acc1 += ws_ * bf16_to_f32(v.y);
    }
    acc0 += b[fi];
    acc1 += b[fi + 1];
    if (do_relu) {
        acc0 = fmaxf(acc0, 0.0f);
        acc1 = fmaxf(acc1, 0.0f);
    }
    if (lane < 48) {
        ushort2 o;
        o.x = f32_to_bf16(acc0);
        o.y = f32_to_bf16(acc1);
        *(ushort2*)(out + (size_t)n * HID + fi) = o;
    }
}

// ---------------------------------------------------------------- pooling ---
// 32-node chunks; fast branch-free path when chunk is within one graph.
#define PCH 32
__global__ __launch_bounds__(96) void pool_kernel(
    const unsigned short* __restrict__ h, const int* __restrict__ batch,
    float* __restrict__ sums, float* __restrict__ cnts, int N) {
    int n0 = blockIdx.x * PCH;
    if (n0 >= N) return;
    int f = threadIdx.x;
    int nend = min(n0 + PCH, N);
    int gfirst = batch[n0];
    int glast = batch[nend - 1];
    if (gfirst == glast) {
        float acc = 0.0f;
#pragma unroll 8
        for (int n = n0; n < nend; n++) acc += bf16_to_f32(h[(size_t)n * HID + f]);
        atomicAdd(&sums[gfirst * HID + f], acc);
        if (f == 0) atomicAdd(&cnts[gfirst], (float)(nend - n0));
        return;
    }
    int g_cur = gfirst;
    float acc = 0.0f, cacc = 0.0f;
    for (int n = n0; n < nend; n++) {
        int g = batch[n];
        if (g != g_cur) {
            atomicAdd(&sums[g_cur * HID + f], acc);
            if (f == 0) atomicAdd(&cnts[g_cur], cacc);
            acc = 0.0f;
            cacc = 0.0f;
            g_cur = g;
        }
        acc += bf16_to_f32(h[(size_t)n * HID + f]);
        cacc += 1.0f;
    }
    atomicAdd(&sums[g_cur * HID + f], acc);
    if (f == 0) atomicAdd(&cnts[g_cur], cacc);
}

// ---------------------------------------------------------------- head ------
__global__ __launch_bounds__(640) void final_kernel(
    const float* __restrict__ sums, const float* __restrict__ cnts,
    const float* __restrict__ Wlin, const float* __restrict__ blin,
    float* __restrict__ out) {
    int t = threadIdx.x;
    if (t >= NGRAPHS * 10) return;
    int g = t / 10;
    int c = t % 10;
    float denom = fmaxf(cnts[g], 1.0f);
    float acc = blin[c];
#pragma unroll
    for (int f = 0; f < HID; f++)
        acc += (sums[g * HID + f] / denom) * Wlin[f * 10 + c];
    out[t] = acc;
}

// ---------------------------------------------------------------- launch ----
extern "C" void kernel_launch(void* const* d_in, const int* in_sizes, int n_in,
                              void* d_out, int out_size, void* d_ws,
                              size_t ws_size, hipStream_t stream) {
    const float* x = (const float*)d_in[0];
    const int* edge = (const int*)d_in[1];
    const int* batch = (const int*)d_in[2];
    const float* W[3] = {(const float*)d_in[3], (const float*)d_in[5],
                         (const float*)d_in[7]};
    const float* B[3] = {(const float*)d_in[4], (const float*)d_in[6],
                         (const float*)d_in[8]};
    const float* Wlin = (const float*)d_in[9];
    const float* blin = (const float*)d_in[10];
    float* out = (float*)d_out;

    int N = in_sizes[0] / HID;  // 50000
    int E = in_sizes[1] / 2;    // 800000
    const int* src = edge;
    const int* dst = edge + E;
    int NB = (N + 255) / 256;   // 196 scan blocks

    // workspace layout (256B-aligned chunks)
    char* ws = (char*)d_ws;
    size_t off = 0;
    auto alloc = [&](size_t bytes) {
        void* p = ws + off;
        off += (bytes + 255) & ~(size_t)255;
        return p;
    };
    int* deg = (int*)alloc((size_t)N * 4);
    float* dinv = (float*)alloc((size_t)N * 4);
    int* rowptr = (int*)alloc(((size_t)N + 1) * 4);
    int* cursor = (int*)alloc((size_t)N * 4);
    int* blocksum = (int*)alloc((size_t)NB * 4);
    int* blockoff = (int*)alloc((size_t)NB * 4);
    int* csr_src = (int*)alloc((size_t)E * 4);
    unsigned short* Wz = (unsigned short*)alloc(3 * HID * HID * 2);
    unsigned short* bufx = (unsigned short*)alloc((size_t)N * HID * 2);
    unsigned short* bufh = (unsigned short*)alloc((size_t)N * HID * 2);
    unsigned short* bufa = (unsigned short*)alloc((size_t)N * HID * 2);
    float* psum = (float*)alloc(NGRAPHS * HID * 4);
    float* pcnt = (float*)alloc(NGRAPHS * 4);

    // --- CSR build + weight prep ---
    hipMemsetAsync(deg, 0, (size_t)N * 4, stream);
    hipMemsetAsync(cursor, 0, (size_t)N * 4, stream);
    deg_kernel<<<(E + 255) / 256, 256, 0, stream>>>(dst, deg, E);
    dinv_kernel<<<(N + 255) / 256, 256, 0, stream>>>(deg, dinv, N);
    scan_phaseA<<<NB, 256, 0, stream>>>(deg, blocksum, N);
    scan_phaseB<<<1, 256, 0, stream>>>(blocksum, blockoff, NB, rowptr, N, E);
    scan_phaseC<<<NB, 256, 0, stream>>>(deg, blockoff, rowptr, N);
    csr_fill<<<(E + 255) / 256, 256, 0, stream>>>(src, dst, rowptr, cursor,
                                                  csr_src, E);
    swizzle_W<<<3, 256, 0, stream>>>(W[0], W[1], W[2], Wz);
    cvt_f32_bf16<<<((size_t)N * HID + 255) / 256, 256, 0, stream>>>(x, bufx,
                                                                    N * HID);

    int Mtiles = (N + 15) / 16;  // 3125
    int gather_grid = (N + 3) / 4;

    unsigned short* act_in = bufx;
    unsigned short* act_out = bufa;
    for (int l = 0; l < 3; l++) {
        gemm_mfma<<<320, 256, 0, stream>>>(act_in, Wz + l * HID * HID, bufh,
                                           Mtiles);
        gcn_gather_bf16<<<gather_grid, 256, 0, stream>>>(
            bufh, rowptr, csr_src, dinv, B[l], act_out, N, l < 2);
        unsigned short* t = act_in;
        act_in = act_out;
        act_out = t;
    }
    hipMemsetAsync(psum, 0, (NGRAPHS * HID + NGRAPHS) * sizeof(float), stream);
    pool_kernel<<<(N + PCH - 1) / PCH, 96, 0, stream>>>(act_in, batch, psum,
                                                        pcnt, N);
    final_kernel<<<1, 640, 0, stream>>>(psum, pcnt, Wlin, blin, out);
}

// Round 5
// 338.557 us; speedup vs baseline: 3.5113x; 1.0871x over previous
//
#include <hip/hip_runtime.h>
#include <hip/hip_bf16.h>

#define HID 96
#define NGRAPHS 64

typedef __attribute__((ext_vector_type(8))) short short8;
typedef __attribute__((ext_vector_type(4))) float floatx4;

__device__ __forceinline__ float bf16_to_f32(unsigned short u) {
    unsigned int v = ((unsigned int)u) << 16;
    return __builtin_bit_cast(float, v);
}
__device__ __forceinline__ unsigned short f32_to_bf16(float f) {
    unsigned int u = __builtin_bit_cast(unsigned int, f);
    u += 0x7fff + ((u >> 16) & 1);  // RNE
    return (unsigned short)(u >> 16);
}

// ---------------------------------------------------------------- degree ----
// 4 edges per thread via int4; independent atomic chains for MLP.
__global__ void deg_kernel(const int* __restrict__ dst, int* __restrict__ deg,
                           int n_edges) {
    int t = blockIdx.x * blockDim.x + threadIdx.x;
    int e0 = t * 4;
    if (e0 + 4 <= n_edges) {
        int4 d4 = *(const int4*)(dst + e0);
        atomicAdd(&deg[d4.x], 1);
        atomicAdd(&deg[d4.y], 1);
        atomicAdd(&deg[d4.z], 1);
        atomicAdd(&deg[d4.w], 1);
    } else {
        for (int e = e0; e < n_edges; e++) atomicAdd(&deg[dst[e]], 1);
    }
}

__global__ void dinv_kernel(const int* __restrict__ deg, float* __restrict__ dinv,
                            int n) {
    int i = blockIdx.x * blockDim.x + threadIdx.x;
    if (i < n) dinv[i] = rsqrtf((float)deg[i] + 1.0f);
}

// ---------------------------------------------------- 3-phase prefix scan ---
__global__ __launch_bounds__(256) void scan_phaseA(const int* __restrict__ deg,
                                                   int* __restrict__ blocksum,
                                                   int N) {
    int i = blockIdx.x * 256 + threadIdx.x;
    int v = (i < N) ? deg[i] : 0;
#pragma unroll
    for (int off = 32; off > 0; off >>= 1) v += __shfl_down(v, off, 64);
    __shared__ int s[4];
    if ((threadIdx.x & 63) == 0) s[threadIdx.x >> 6] = v;
    __syncthreads();
    if (threadIdx.x == 0) blocksum[blockIdx.x] = s[0] + s[1] + s[2] + s[3];
}

__global__ __launch_bounds__(256) void scan_phaseB(int* __restrict__ blocksum,
                                                   int* __restrict__ blockoff,
                                                   int nblocks, int* __restrict__ rowptr,
                                                   int N, int E) {
    __shared__ int s[256];
    int t = threadIdx.x;
    int own = (t < nblocks) ? blocksum[t] : 0;
    s[t] = own;
    __syncthreads();
#pragma unroll
    for (int off = 1; off < 256; off <<= 1) {
        int v = (t >= off) ? s[t - off] : 0;
        __syncthreads();
        s[t] += v;
        __syncthreads();
    }
    if (t < nblocks) blockoff[t] = s[t] - own;  // exclusive
    if (t == 0) rowptr[N] = E;
}

__global__ __launch_bounds__(256) void scan_phaseC(const int* __restrict__ deg,
                                                   const int* __restrict__ blockoff,
                                                   int* __restrict__ rowptr,
                                                   int* __restrict__ cursor, int N) {
    __shared__ int s[256];
    int t = threadIdx.x;
    int i = blockIdx.x * 256 + t;
    int own = (i < N) ? deg[i] : 0;
    s[t] = own;
    __syncthreads();
#pragma unroll
    for (int off = 1; off < 256; off <<= 1) {
        int v = (t >= off) ? s[t - off] : 0;
        __syncthreads();
        s[t] += v;
        __syncthreads();
    }
    if (i < N) {
        int r = blockoff[blockIdx.x] + s[t] - own;
        rowptr[i] = r;
        cursor[i] = r;  // seed cursor with rowptr: atomics return absolute pos
    }
}

// ------------------------------------------------------------------ fill ----
// cursor pre-seeded with rowptr; 4 edges/thread via int4; ushort payload.
__global__ void csr_fill(const int* __restrict__ src, const int* __restrict__ dst,
                         int* __restrict__ cursor,
                         unsigned short* __restrict__ csr_src, int n_edges) {
    int t = blockIdx.x * blockDim.x + threadIdx.x;
    int e0 = t * 4;
    if (e0 + 4 <= n_edges) {
        int4 d4 = *(const int4*)(dst + e0);
        int4 s4 = *(const int4*)(src + e0);
        int p0 = atomicAdd(&cursor[d4.x], 1);
        int p1 = atomicAdd(&cursor[d4.y], 1);
        int p2 = atomicAdd(&cursor[d4.z], 1);
        int p3 = atomicAdd(&cursor[d4.w], 1);
        csr_src[p0] = (unsigned short)s4.x;
        csr_src[p1] = (unsigned short)s4.y;
        csr_src[p2] = (unsigned short)s4.z;
        csr_src[p3] = (unsigned short)s4.w;
    } else {
        for (int e = e0; e < n_edges; e++) {
            int p = atomicAdd(&cursor[dst[e]], 1);
            csr_src[p] = (unsigned short)src[e];
        }
    }
}

// --------------------------------------------------------------- convert ----
__global__ void cvt_f32_bf16(const float* __restrict__ in,
                             unsigned short* __restrict__ out, int n4) {
    int i = blockIdx.x * blockDim.x + threadIdx.x;
    if (i < n4) {
        float4 v = *(const float4*)(in + i * 4);
        ushort4 o;
        o.x = f32_to_bf16(v.x);
        o.y = f32_to_bf16(v.y);
        o.z = f32_to_bf16(v.z);
        o.w = f32_to_bf16(v.w);
        *(ushort4*)(out + i * 4) = o;
    }
}

// W[96][96] f32 -> bf16 in MFMA B-fragment order.
__global__ void swizzle_W(const float* __restrict__ W0, const float* __restrict__ W1,
                          const float* __restrict__ W2, unsigned short* __restrict__ Wz) {
    const float* W = (blockIdx.x == 0) ? W0 : (blockIdx.x == 1) ? W1 : W2;
    unsigned short* dst = Wz + blockIdx.x * HID * HID;
    for (int e = threadIdx.x; e < HID * HID; e += blockDim.x) {
        int k = e / HID, n = e % HID;
        int nt = n >> 4, kki = k >> 5, quad = (k >> 3) & 3, j = k & 7;
        int lane = (n & 15) | (quad << 4);
        dst[(((nt * 3 + kki) * 64 + lane) << 3) | j] = f32_to_bf16(W[e]);
    }
}

// ------------------------------------------------------------- MFMA GEMM ----
// Out[m] = (A[m] @ W) * dinv[m]   (prescaled for the gather)
__global__ __launch_bounds__(256) void gemm_mfma(
    const unsigned short* __restrict__ A, const unsigned short* __restrict__ Wz,
    const float* __restrict__ dinv, unsigned short* __restrict__ Out, int Mtiles) {
    int wave = threadIdx.x >> 6;
    int lane = threadIdx.x & 63;
    int quad = lane >> 4;
    int mrow = lane & 15;

    short8 bfrag[18];
    const short8* Wz8 = (const short8*)Wz;
#pragma unroll
    for (int f = 0; f < 18; f++) bfrag[f] = Wz8[f * 64 + lane];

    for (int tt = blockIdx.x * 4 + wave; tt < Mtiles; tt += gridDim.x * 4) {
        int m0 = tt * 16;
        const unsigned short* arow = A + (size_t)(m0 + mrow) * HID + quad * 8;
        short8 a0 = *(const short8*)(arow);
        short8 a1 = *(const short8*)(arow + 32);
        short8 a2 = *(const short8*)(arow + 64);
        float dscale[4];
#pragma unroll
        for (int r = 0; r < 4; r++) dscale[r] = dinv[m0 + quad * 4 + r];
        floatx4 acc[6];
#pragma unroll
        for (int nt = 0; nt < 6; nt++) {
            floatx4 c = {0.0f, 0.0f, 0.0f, 0.0f};
            c = __builtin_amdgcn_mfma_f32_16x16x32_bf16(a0, bfrag[nt * 3 + 0], c, 0, 0, 0);
            c = __builtin_amdgcn_mfma_f32_16x16x32_bf16(a1, bfrag[nt * 3 + 1], c, 0, 0, 0);
            c = __builtin_amdgcn_mfma_f32_16x16x32_bf16(a2, bfrag[nt * 3 + 2], c, 0, 0, 0);
            acc[nt] = c;
        }
        unsigned short* orow = Out + (size_t)m0 * HID;
#pragma unroll
        for (int nt = 0; nt < 6; nt++)
#pragma unroll
            for (int r = 0; r < 4; r++) {
                int row = quad * 4 + r;  // C/D: col=lane&15, row=quad*4+reg
                orow[(size_t)row * HID + nt * 16 + mrow] =
                    f32_to_bf16(acc[nt][r] * dscale[r]);
            }
    }
}

// ---------------------------------------------------------------- gather ----
// h is prescaled (h' = h*dinv). out[n] = (h'[n] + sum h'[src]) * dinv[n] + b.
// 8-wide index-prefetch: 8 independent idx loads, then 8 independent row loads.
__global__ __launch_bounds__(256) void gcn_gather_bf16(
    const unsigned short* __restrict__ h, const int* __restrict__ rowptr,
    const unsigned short* __restrict__ csr_src, const float* __restrict__ dinv,
    const float* __restrict__ b, unsigned short* __restrict__ out, int N,
    int do_relu) {
    int wv = threadIdx.x >> 6;
    int lane = threadIdx.x & 63;
    int n = blockIdx.x * 4 + wv;
    if (n >= N) return;
    int fi = (lane < 48) ? lane * 2 : 94;  // idle lanes duplicate lane 47
    int start = rowptr[n];
    int end = rowptr[n + 1];
    float di = dinv[n];

    ushort2 hv = *(const ushort2*)(h + (size_t)n * HID + fi);
    float acc0 = bf16_to_f32(hv.x);
    float acc1 = bf16_to_f32(hv.y);

    int i = start;
    for (; i + 8 <= end; i += 8) {
        int s0 = csr_src[i + 0];
        int s1 = csr_src[i + 1];
        int s2 = csr_src[i + 2];
        int s3 = csr_src[i + 3];
        int s4 = csr_src[i + 4];
        int s5 = csr_src[i + 5];
        int s6 = csr_src[i + 6];
        int s7 = csr_src[i + 7];
        ushort2 v0 = *(const ushort2*)(h + (size_t)s0 * HID + fi);
        ushort2 v1 = *(const ushort2*)(h + (size_t)s1 * HID + fi);
        ushort2 v2 = *(const ushort2*)(h + (size_t)s2 * HID + fi);
        ushort2 v3 = *(const ushort2*)(h + (size_t)s3 * HID + fi);
        ushort2 v4 = *(const ushort2*)(h + (size_t)s4 * HID + fi);
        ushort2 v5 = *(const ushort2*)(h + (size_t)s5 * HID + fi);
        ushort2 v6 = *(const ushort2*)(h + (size_t)s6 * HID + fi);
        ushort2 v7 = *(const ushort2*)(h + (size_t)s7 * HID + fi);
        acc0 += bf16_to_f32(v0.x) + bf16_to_f32(v1.x) + bf16_to_f32(v2.x) +
                bf16_to_f32(v3.x) + bf16_to_f32(v4.x) + bf16_to_f32(v5.x) +
                bf16_to_f32(v6.x) + bf16_to_f32(v7.x);
        acc1 += bf16_to_f32(v0.y) + bf16_to_f32(v1.y) + bf16_to_f32(v2.y) +
                bf16_to_f32(v3.y) + bf16_to_f32(v4.y) + bf16_to_f32(v5.y) +
                bf16_to_f32(v6.y) + bf16_to_f32(v7.y);
    }
#pragma unroll 4
    for (; i < end; i++) {
        int s = csr_src[i];
        ushort2 v = *(const ushort2*)(h + (size_t)s * HID + fi);
        acc0 += bf16_to_f32(v.x);
        acc1 += bf16_to_f32(v.y);
    }
    acc0 = acc0 * di + b[fi];
    acc1 = acc1 * di + b[fi + 1];
    if (do_relu) {
        acc0 = fmaxf(acc0, 0.0f);
        acc1 = fmaxf(acc1, 0.0f);
    }
    if (lane < 48) {
        ushort2 o;
        o.x = f32_to_bf16(acc0);
        o.y = f32_to_bf16(acc1);
        *(ushort2*)(out + (size_t)n * HID + fi) = o;
    }
}

// ---------------------------------------------------------------- pooling ---
#define PCH 32
__global__ __launch_bounds__(96) void pool_kernel(
    const unsigned short* __restrict__ h, const int* __restrict__ batch,
    float* __restrict__ sums, float* __restrict__ cnts, int N) {
    int n0 = blockIdx.x * PCH;
    if (n0 >= N) return;
    int f = threadIdx.x;
    int nend = min(n0 + PCH, N);
    int gfirst = batch[n0];
    int glast = batch[nend - 1];
    if (gfirst == glast) {
        float acc = 0.0f;
#pragma unroll 8
        for (int n = n0; n < nend; n++) acc += bf16_to_f32(h[(size_t)n * HID + f]);
        atomicAdd(&sums[gfirst * HID + f], acc);
        if (f == 0) atomicAdd(&cnts[gfirst], (float)(nend - n0));
        return;
    }
    int g_cur = gfirst;
    float acc = 0.0f, cacc = 0.0f;
    for (int n = n0; n < nend; n++) {
        int g = batch[n];
        if (g != g_cur) {
            atomicAdd(&sums[g_cur * HID + f], acc);
            if (f == 0) atomicAdd(&cnts[g_cur], cacc);
            acc = 0.0f;
            cacc = 0.0f;
            g_cur = g;
        }
        acc += bf16_to_f32(h[(size_t)n * HID + f]);
        cacc += 1.0f;
    }
    atomicAdd(&sums[g_cur * HID + f], acc);
    if (f == 0) atomicAdd(&cnts[g_cur], cacc);
}

// ---------------------------------------------------------------- head ------
__global__ __launch_bounds__(640) void final_kernel(
    const float* __restrict__ sums, const float* __restrict__ cnts,
    const float* __restrict__ Wlin, const float* __restrict__ blin,
    float* __restrict__ out) {
    int t = threadIdx.x;
    if (t >= NGRAPHS * 10) return;
    int g = t / 10;
    int c = t % 10;
    float denom = fmaxf(cnts[g], 1.0f);
    float acc = blin[c];
#pragma unroll
    for (int f = 0; f < HID; f++)
        acc += (sums[g * HID + f] / denom) * Wlin[f * 10 + c];
    out[t] = acc;
}

// ---------------------------------------------------------------- launch ----
extern "C" void kernel_launch(void* const* d_in, const int* in_sizes, int n_in,
                              void* d_out, int out_size, void* d_ws,
                              size_t ws_size, hipStream_t stream) {
    const float* x = (const float*)d_in[0];
    const int* edge = (const int*)d_in[1];
    const int* batch = (const int*)d_in[2];
    const float* W[3] = {(const float*)d_in[3], (const float*)d_in[5],
                         (const float*)d_in[7]};
    const float* B[3] = {(const float*)d_in[4], (const float*)d_in[6],
                         (const float*)d_in[8]};
    const float* Wlin = (const float*)d_in[9];
    const float* blin = (const float*)d_in[10];
    float* out = (float*)d_out;

    int N = in_sizes[0] / HID;  // 50000
    int E = in_sizes[1] / 2;    // 800000
    const int* src = edge;
    const int* dst = edge + E;
    int NB = (N + 255) / 256;

    // workspace layout (256B-aligned chunks)
    char* ws = (char*)d_ws;
    size_t off = 0;
    auto alloc = [&](size_t bytes) {
        void* p = ws + off;
        off += (bytes + 255) & ~(size_t)255;
        return p;
    };
    int* deg = (int*)alloc((size_t)N * 4);
    float* dinv = (float*)alloc((size_t)N * 4);
    int* rowptr = (int*)alloc(((size_t)N + 1) * 4);
    int* cursor = (int*)alloc((size_t)N * 4);
    int* blocksum = (int*)alloc((size_t)NB * 4);
    int* blockoff = (int*)alloc((size_t)NB * 4);
    unsigned short* csr_src = (unsigned short*)alloc((size_t)E * 2);
    unsigned short* Wz = (unsigned short*)alloc(3 * HID * HID * 2);
    unsigned short* bufx = (unsigned short*)alloc((size_t)N * HID * 2);
    unsigned short* bufh = (unsigned short*)alloc((size_t)N * HID * 2);
    unsigned short* bufa = (unsigned short*)alloc((size_t)N * HID * 2);
    float* psum = (float*)alloc(NGRAPHS * HID * 4);
    float* pcnt = (float*)alloc(NGRAPHS * 4);

    // --- CSR build + weight prep ---
    hipMemsetAsync(deg, 0, (size_t)N * 4, stream);
    deg_kernel<<<(E / 4 + 255) / 256, 256, 0, stream>>>(dst, deg, E);
    dinv_kernel<<<(N + 255) / 256, 256, 0, stream>>>(deg, dinv, N);
    scan_phaseA<<<NB, 256, 0, stream>>>(deg, blocksum, N);
    scan_phaseB<<<1, 256, 0, stream>>>(blocksum, blockoff, NB, rowptr, N, E);
    scan_phaseC<<<NB, 256, 0, stream>>>(deg, blockoff, rowptr, cursor, N);
    csr_fill<<<(E / 4 + 255) / 256, 256, 0, stream>>>(src, dst, cursor, csr_src, E);
    swizzle_W<<<3, 256, 0, stream>>>(W[0], W[1], W[2], Wz);
    cvt_f32_bf16<<<((size_t)N * HID / 4 + 255) / 256, 256, 0, stream>>>(
        x, bufx, N * HID / 4);

    int Mtiles = (N + 15) / 16;  // 3125
    int gather_grid = (N + 3) / 4;

    unsigned short* act_in = bufx;
    unsigned short* act_out = bufa;
    for (int l = 0; l < 3; l++) {
        gemm_mfma<<<640, 256, 0, stream>>>(act_in, Wz + l * HID * HID, dinv,
                                           bufh, Mtiles);
        gcn_gather_bf16<<<gather_grid, 256, 0, stream>>>(
            bufh, rowptr, csr_src, dinv, B[l], act_out, N, l < 2);
        unsigned short* t = act_in;
        act_in = act_out;
        act_out = t;
    }
    hipMemsetAsync(psum, 0, (NGRAPHS * HID + NGRAPHS) * sizeof(float), stream);
    pool_kernel<<<(N + PCH - 1) / PCH, 96, 0, stream>>>(act_in, batch, psum,
                                                        pcnt, N);
    final_kernel<<<1, 640, 0, stream>>>(psum, pcnt, Wlin, blin, out);
}